// Round 1
// baseline (132.327 us; speedup 1.0000x reference)
//
#include <hip/hip_runtime.h>

#define B_TOT 4096
#define NWS 64  // scratch accumulators in d_ws

__global__ void zero_ws_kernel(float* ws) {
    ws[threadIdx.x] = 0.f;
}

__global__ __launch_bounds__(256) void energy_kernel(
    const float* __restrict__ grid,
    const float* __restrict__ hints,
    const float* __restrict__ w_g,
    const float* __restrict__ w_h,
    float* __restrict__ ws)
{
    const int b   = blockIdx.x;
    const int tid = threadIdx.x;

    __shared__ float s[64 * 65];     // sigmoid matrix, padded stride 65
    __shared__ float target[2][64];  // [0]=row targets, [1]=col targets
    __shared__ int   s_size;
    __shared__ float red[4];

    // ---- Phase A: hints. Thread covers floats [8*tid, 8*tid+8).
    // Row index t = tid>>1 (= c*64+i), half = tid&1.
    const float* hb = hints + (size_t)b * 2048;
    float4 h0 = *(const float4*)(hb + 8 * tid);
    float4 h1 = *(const float4*)(hb + 8 * tid + 4);
    float4 w0 = *(const float4*)(w_h + 8 * tid);
    float4 w1 = *(const float4*)(w_h + 8 * tid + 4);
    float dot_h = h0.x * w0.x + h0.y * w0.y + h0.z * w0.z + h0.w * w0.w
                + h1.x * w1.x + h1.y * w1.y + h1.z * w1.z + h1.w * w1.w;
    float hsum = h0.x + h0.y + h0.z + h0.w + h1.x + h1.y + h1.z + h1.w;
    hsum += __shfl_xor(hsum, 1);           // pair (2t, 2t+1) -> full 16-sum
    if ((tid & 1) == 0) {
        target[tid >> 7][(tid >> 1) & 63] = hsum;
    }
    __syncthreads();

    // ---- Phase B: derive size from last nonzero row/col target (wave 0).
    if (tid < 64) {
        unsigned long long mr = __ballot(target[0][tid] > 0.f);
        unsigned long long mc = __ballot(target[1][tid] > 0.f);
        if (tid == 0) {
            int last_r = mr ? (63 - __builtin_clzll(mr)) : -1;
            int last_c = mc ? (63 - __builtin_clzll(mc)) : -1;
            s_size = (last_r >= 0 && last_c >= 0) ? (max(last_r, last_c) + 1)
                                                  : 12;  // FALLBACK_SIZE
        }
    }
    __syncthreads();
    const int   size = s_size;
    const float sz   = (float)size;

    // ---- Phase C: grid. 4 float4 per thread; neural dot, bin term, sigmoid->LDS.
    const float* gb = grid + (size_t)b * 4096;
    float neural = dot_h;
    float binp   = 0.f;
    #pragma unroll
    for (int k = 0; k < 4; ++k) {
        int q = tid + 256 * k;                 // float4 index in [0,1024)
        float4 g = *(const float4*)(gb + 4 * q);
        float4 w = *(const float4*)(w_g + 4 * q);
        neural += g.x * w.x + g.y * w.y + g.z * w.z + g.w * w.w;
        int row = q >> 4;
        int c0  = (q & 15) * 4;
        if (row < size) {
            float bs = 0.f;
            if (c0 + 0 < size) bs += g.x * g.x;
            if (c0 + 1 < size) bs += g.y * g.y;
            if (c0 + 2 < size) bs += g.z * g.z;
            if (c0 + 3 < size) bs += g.w * g.w;
            binp += bs;
        }
        float* sp = s + row * 65 + c0;
        sp[0] = 1.f / (1.f + __expf(-3.f * g.x));
        sp[1] = 1.f / (1.f + __expf(-3.f * g.y));
        sp[2] = 1.f / (1.f + __expf(-3.f * g.z));
        sp[3] = 1.f / (1.f + __expf(-3.f * g.w));
    }
    __syncthreads();

    // ---- Phase D: row errors. 4 lanes per row, 16 cols each.
    float errp = 0.f;
    {
        int r = tid >> 2, qq = tid & 3;
        float acc = 0.f;
        #pragma unroll
        for (int x = 0; x < 16; ++x) {
            int j = 16 * qq + x;
            acc += (j < size) ? s[r * 65 + j] : 0.f;
        }
        acc += __shfl_xor(acc, 1);
        acc += __shfl_xor(acc, 2);
        if (qq == 0 && r < size) {
            float d = acc - target[0][r];
            errp += d * d;
        }
    }
    // ---- col errors. 4 lanes per col, 16 rows each (stride-65 = 2-way bank, free).
    {
        int c = tid >> 2, qq = tid & 3;
        float acc = 0.f;
        #pragma unroll
        for (int x = 0; x < 16; ++x) {
            int i = 16 * qq + x;
            acc += (i < size) ? s[i * 65 + c] : 0.f;
        }
        acc += __shfl_xor(acc, 1);
        acc += __shfl_xor(acc, 2);
        if (qq == 0 && c < size) {
            float d = acc - target[1][c];
            errp += d * d;
        }
    }

    // ---- combine + block reduce
    float v = neural + errp * (10.f / sz) + binp * (0.1f / (sz * sz));
    #pragma unroll
    for (int off = 1; off < 64; off <<= 1) v += __shfl_xor(v, off);
    if ((tid & 63) == 0) red[tid >> 6] = v;
    __syncthreads();
    if (tid == 0) {
        float tot = (red[0] + red[1] + red[2] + red[3]) * (1.f / (float)B_TOT);
        atomicAdd(&ws[b & (NWS - 1)], tot);
    }
}

__global__ void final_reduce_kernel(const float* __restrict__ ws,
                                    float* __restrict__ out) {
    float v = ws[threadIdx.x];
    #pragma unroll
    for (int off = 1; off < 64; off <<= 1) v += __shfl_xor(v, off);
    if (threadIdx.x == 0) out[0] = v;
}

extern "C" void kernel_launch(void* const* d_in, const int* in_sizes, int n_in,
                              void* d_out, int out_size, void* d_ws, size_t ws_size,
                              hipStream_t stream) {
    const float* grid_p  = (const float*)d_in[0];
    const float* hints_p = (const float*)d_in[1];
    const float* w_g     = (const float*)d_in[2];
    const float* w_h     = (const float*)d_in[3];
    float* out = (float*)d_out;
    float* ws  = (float*)d_ws;

    zero_ws_kernel<<<1, NWS, 0, stream>>>(ws);
    energy_kernel<<<B_TOT, 256, 0, stream>>>(grid_p, hints_p, w_g, w_h, ws);
    final_reduce_kernel<<<1, 64, 0, stream>>>(ws, out);
}

// Round 2
// 120.044 us; speedup vs baseline: 1.1023x; 1.1023x over previous
//
#include <hip/hip_runtime.h>

#define B_TOT 4096

__global__ __launch_bounds__(256) void energy_kernel(
    const float* __restrict__ grid,
    const float* __restrict__ hints,
    const float* __restrict__ w_g,
    const float* __restrict__ w_h,
    float* __restrict__ ws)
{
    const int b    = blockIdx.x;
    const int tid  = threadIdx.x;
    const int lane = tid & 63;
    const int wv   = tid >> 6;

    __shared__ float  target[2][64];
    __shared__ float4 colp4[4][16];   // per-wave column partials (64 cols)
    __shared__ int    s_size;
    __shared__ float  red[4];

    const float* hb = hints + (size_t)b * 2048;
    const float* gb = grid  + (size_t)b * 4096;

    // ---- Issue ALL global loads up front so they're in flight during the
    // hint/size phase (grid consumption is behind two barriers otherwise).
    float4 h0 = *(const float4*)(hb + 8 * tid);
    float4 h1 = *(const float4*)(hb + 8 * tid + 4);
    float4 g0 = *(const float4*)(gb + 4 * tid);
    float4 g1 = *(const float4*)(gb + 4 * tid + 1024);
    float4 g2 = *(const float4*)(gb + 4 * tid + 2048);
    float4 g3 = *(const float4*)(gb + 4 * tid + 3072);
    float4 wh0 = *(const float4*)(w_h + 8 * tid);
    float4 wh1 = *(const float4*)(w_h + 8 * tid + 4);
    float4 wg0 = *(const float4*)(w_g + 4 * tid);
    float4 wg1 = *(const float4*)(w_g + 4 * tid + 1024);
    float4 wg2 = *(const float4*)(w_g + 4 * tid + 2048);
    float4 wg3 = *(const float4*)(w_g + 4 * tid + 3072);

    // ---- Phase A: hint dot + row/col targets. Thread covers hint row tid>>1, half tid&1.
    float neural = h0.x * wh0.x + h0.y * wh0.y + h0.z * wh0.z + h0.w * wh0.w
                 + h1.x * wh1.x + h1.y * wh1.y + h1.z * wh1.z + h1.w * wh1.w;
    float hsum = h0.x + h0.y + h0.z + h0.w + h1.x + h1.y + h1.z + h1.w;
    hsum += __shfl_xor(hsum, 1);  // pair (2t,2t+1) -> full 16-sum
    if ((tid & 1) == 0) target[tid >> 7][(tid >> 1) & 63] = hsum;
    __syncthreads();

    // ---- Phase B: size from last nonzero row/col target (wave 0; ballot is wave-uniform).
    if (tid < 64) {
        unsigned long long mr = __ballot(target[0][tid] > 0.f);
        unsigned long long mc = __ballot(target[1][tid] > 0.f);
        if (tid == 0) {
            int last_r = mr ? (63 - __builtin_clzll(mr)) : -1;
            int last_c = mc ? (63 - __builtin_clzll(mc)) : -1;
            s_size = (last_r >= 0 && last_c >= 0) ? (max(last_r, last_c) + 1) : 12;
        }
    }
    __syncthreads();
    const int   size = s_size;
    const float sz   = (float)size;

    // ---- Phase C: grid terms, all in registers.
    // q = tid + 256k; row = (tid>>4)+16k; cols c0..c0+3, c0=(tid&15)*4.
    const int c0   = (tid & 15) * 4;
    const int rbase = tid >> 4;
    // column validity (per component)
    const float mx = (c0 + 0 < size) ? 1.f : 0.f;
    const float my = (c0 + 1 < size) ? 1.f : 0.f;
    const float mz = (c0 + 2 < size) ? 1.f : 0.f;
    const float mw = (c0 + 3 < size) ? 1.f : 0.f;

    float binp = 0.f;
    float errp = 0.f;
    float4 cacc = {0.f, 0.f, 0.f, 0.f};

    float4 gk[4] = {g0, g1, g2, g3};
    float4 wk[4] = {wg0, wg1, wg2, wg3};
    #pragma unroll
    for (int k = 0; k < 4; ++k) {
        float4 g = gk[k];
        float4 w = wk[k];
        neural += g.x * w.x + g.y * w.y + g.z * w.z + g.w * w.w;
        int   row  = rbase + 16 * k;
        float rmask = (row < size) ? 1.f : 0.f;
        binp += rmask * (mx * g.x * g.x + my * g.y * g.y + mz * g.z * g.z + mw * g.w * g.w);

        float sx = 1.f / (1.f + __expf(-3.f * g.x));
        float sy = 1.f / (1.f + __expf(-3.f * g.y));
        float sz_ = 1.f / (1.f + __expf(-3.f * g.z));
        float sw = 1.f / (1.f + __expf(-3.f * g.w));

        // row sum: 16 consecutive lanes hold one row
        float rs = mx * sx + my * sy + mz * sz_ + mw * sw;
        rs += __shfl_xor(rs, 1);
        rs += __shfl_xor(rs, 2);
        rs += __shfl_xor(rs, 4);
        rs += __shfl_xor(rs, 8);
        if ((lane & 15) == 0 && row < size) {
            float d = rs - target[0][row];
            errp += d * d;
        }

        // column accumulation (masked by row validity)
        cacc.x += rmask * sx;
        cacc.y += rmask * sy;
        cacc.z += rmask * sz_;
        cacc.w += rmask * sw;
    }

    // reduce column partials across the 4 row-groups in this wave (lanes stride 16)
    cacc.x += __shfl_xor(cacc.x, 16); cacc.x += __shfl_xor(cacc.x, 32);
    cacc.y += __shfl_xor(cacc.y, 16); cacc.y += __shfl_xor(cacc.y, 32);
    cacc.z += __shfl_xor(cacc.z, 16); cacc.z += __shfl_xor(cacc.z, 32);
    cacc.w += __shfl_xor(cacc.w, 16); cacc.w += __shfl_xor(cacc.w, 32);
    if (lane < 16) colp4[wv][lane] = cacc;   // 16B-aligned store
    __syncthreads();

    // column errors: 64 threads, one column each; read 4 wave-partials (2-way bank, free)
    if (tid < 64) {
        const float* cp = (const float*)colp4;
        float csum = cp[tid] + cp[64 + tid] + cp[128 + tid] + cp[192 + tid];
        if (tid < size) {
            float d = csum - target[1][tid];
            errp += d * d;
        }
    }

    // ---- combine + block reduce -> per-block partial (plain store, no init needed)
    float v = neural + errp * (10.f / sz) + binp * (0.1f / (sz * sz));
    #pragma unroll
    for (int off = 1; off < 64; off <<= 1) v += __shfl_xor(v, off);
    if (lane == 0) red[wv] = v;
    __syncthreads();
    if (tid == 0) ws[b] = red[0] + red[1] + red[2] + red[3];
}

__global__ __launch_bounds__(1024) void final_reduce_kernel(
    const float* __restrict__ ws, float* __restrict__ out)
{
    const int tid = threadIdx.x;
    float4 v4 = ((const float4*)ws)[tid];       // 4096 floats / 1024 threads
    float v = v4.x + v4.y + v4.z + v4.w;
    #pragma unroll
    for (int off = 1; off < 64; off <<= 1) v += __shfl_xor(v, off);
    __shared__ float r[16];
    if ((tid & 63) == 0) r[tid >> 6] = v;
    __syncthreads();
    if (tid < 16) {
        float t = r[tid];
        t += __shfl_xor(t, 1);
        t += __shfl_xor(t, 2);
        t += __shfl_xor(t, 4);
        t += __shfl_xor(t, 8);
        if (tid == 0) out[0] = t * (1.f / (float)B_TOT);
    }
}

extern "C" void kernel_launch(void* const* d_in, const int* in_sizes, int n_in,
                              void* d_out, int out_size, void* d_ws, size_t ws_size,
                              hipStream_t stream) {
    const float* grid_p  = (const float*)d_in[0];
    const float* hints_p = (const float*)d_in[1];
    const float* w_g     = (const float*)d_in[2];
    const float* w_h     = (const float*)d_in[3];
    float* out = (float*)d_out;
    float* ws  = (float*)d_ws;

    energy_kernel<<<B_TOT, 256, 0, stream>>>(grid_p, hints_p, w_g, w_h, ws);
    final_reduce_kernel<<<1, 1024, 0, stream>>>(ws, out);
}